// Round 2
// 89.650 us; speedup vs baseline: 1.0048x; 1.0048x over previous
//
#include <hip/hip_runtime.h>
#include <hip/hip_bf16.h>

#define C1_CONST 4.7e-9f
#define CHUNK 5       // output steps per chunk (3000 waves -> ~2.9 waves/SIMD)
#define WARM  10      // warm-up steps; |rho|~0.5 measured -> init err ~5e-4 < f16 floor
#define CPW   32      // chunks per wave (MFMA batch)

typedef _Float16 f16;
typedef unsigned int u32;
typedef f16   f16x2  __attribute__((ext_vector_type(2)));
typedef f16   f16x8  __attribute__((ext_vector_type(8)));
typedef u32   u32x4  __attribute__((ext_vector_type(4)));
typedef float f32x16 __attribute__((ext_vector_type(16)));

#define MFMA(A, B, C) __builtin_amdgcn_mfma_f32_32x32x16_f16((A), (B), (C), 0, 0, 0)

// Pack two f32 -> packed f16 pair (single v_cvt_pkrtz, RTZ).
__device__ __forceinline__ u32 packp(float x0, float x1) {
    return __builtin_bit_cast(u32, __builtin_amdgcn_cvt_pkrtz(x0, x1));
}

// r15 = r14 with two fixes:
//  * permlane32_swap BUG: with pa==pb==pd the instruction (swap dst-hi with
//    src-lo) yields pa[l]=pd[l&31], pb[l]=pd[l|32] -- full-wave broadcasts of
//    each half. r14's select returned each lane's OWN pd (dp_b = 2*pd+bo).
//    Correct combine is simply dp_b = pa + pb + bo on every lane: lane-wise
//    pd[c]+pd[c+32], same add order in both halves -> bit-identical carries.
//  * Input MFMA residual split: r14 quantized dp_a/dr to f16 entering the
//    input layer (r13 ran it in f32). A has free k-slots, so replicate the
//    two input weights at k=2,3 and feed res = x - f16_rtz(x) there; MFMA
//    accumulates in f32 -> input re-enters at ~f32 precision. Only W_in's
//    own f16 rounding remains (~3.4e-4 * |x|, at the hidden-layer f16 floor).
//
// Structure carried from r14:
//  * Input layer 2->32 folded into a 5th MFMA (kills the 48 persistent f32
//    input-layer constants whose liveness forced per-step remat global loads).
//  * amdgpu_waves_per_eu(2,3): grid is 2.9 waves/SIMD; occupancy >3 is waste,
//    so give RA license to keep constants resident.
//  * Cross-half reduce via v_permlane32_swap_b32 (VALU) instead of ds_bpermute.
//
// LOGICAL-K REMAP (exact): k = (jj&3) + 4*h + 8*(jj>>2) + 16*s, so half h's
// B k-set equals the C/D rows it owns (row=(reg&3)+8*(reg>>2)+4*h) and
// D reg r = jj + 8*s: B0 = relu(D[0..7]), B1 = relu(D[8..15]).
//
// Uses the P0 == 1 identity (g0 = g1+g2 exactly), so the a0 carry vanishes:
//   dp_a = P1*b1 + P2*v,  b1' = dp_a + dp_b - b1,  out = 0.5*(dp_a+dp_b)
__global__ __attribute__((amdgpu_flat_work_group_size(64, 64), amdgpu_waves_per_eu(2, 3)))
void scan_kernel(
    const float* __restrict__ v_in, const float* __restrict__ vs_r,
    const float* __restrict__ fs,
    const float* __restrict__ W_in, const float* __restrict__ b_in,
    const float* __restrict__ W_h,  const float* __restrict__ b_h,
    const float* __restrict__ W_out, const float* __restrict__ b_out,
    float* __restrict__ out, int T) {
    const int lane = threadIdx.x & 63;
    const int c    = lane & 31;   // chunk slot / MFMA col / weight row m
    const int h    = lane >> 5;

    // ---- MFMA A fragments (f16) for the two hidden layers ----
    f16x8 AA0, AA1, AB0, AB1;
#pragma unroll
    for (int jj = 0; jj < 8; ++jj) {
        int k0 = (jj & 3) + 4 * h + 8 * (jj >> 2);   // s=0
        int k1 = k0 + 16;                            // s=1
        AA0[jj] = (f16)W_h[c * 32 + k0];
        AA1[jj] = (f16)W_h[c * 32 + k1];
        AB0[jj] = (f16)W_h[1024 + c * 32 + k0];
        AB1[jj] = (f16)W_h[1024 + c * 32 + k1];
    }

    // ---- input-layer MFMA A fragment (h==0 lanes only hold k=0..3,8..11):
    //      k=0,1 : weights on (dp_a, dr);  k=2,3 : SAME weights for the
    //      f16-residual refinement terms.
    f16x8 AIN;
#pragma unroll
    for (int jj = 0; jj < 8; ++jj) AIN[jj] = (f16)0.0f;
    if (h == 0) {
        f16 w0 = (f16)W_in[2 * c];
        f16 w1 = (f16)W_in[2 * c + 1];
        AIN[0] = w0;   // k=0: hi(dp_a)
        AIN[1] = w1;   // k=1: hi(dr)
        AIN[2] = w0;   // k=2: res(dp_a)
        AIN[3] = w1;   // k=3: res(dr)
    }

    // ---- biases in C/D layout; W_out by C/D row ----
    f32x16 bINf, bAf, bBf;
    float wo_r[16];
#pragma unroll
    for (int r = 0; r < 16; ++r) {
        int row = (r & 3) + 8 * (r >> 2) + 4 * h;
        bINf[r] = b_in[row];
        bAf[r]  = b_h[row];
        bBf[r]  = b_h[32 + row];
        wo_r[r] = W_out[row];
    }
    const float bo = b_out[0];
    const u32 hm   = h ? 0u : 0xFFFFFFFFu;   // kills B_x on h==1 lanes (belt+braces)

    const int cg = blockIdx.x * CPW + c;   // global chunk id
    const int ts = cg * CHUNK;             // first output step of this chunk

    // Inline per-step scalars: g1 = 2*C1*fs, g2 ~= 1/vs_r, inv ~= 1/(g1+g2);
    // P1 = g1*inv, pv = g2*inv*v, dr = inv/3000   (r0 = 1/(g1+g2) exactly).
    auto load_pre = [&](int tt, float& P1, float& pv, float& dr) {
        int tc = min(max(tt, 0), T - 1);
        float f  = fs[tc];
        float vr = vs_r[tc];
        float vv = v_in[tc];
        float g1 = (2.0f * C1_CONST) * f;
        float g2 = __builtin_amdgcn_rcpf(vr);
        float inv = __builtin_amdgcn_rcpf(g1 + g2);
        P1 = g1 * inv;
        pv = g2 * inv * vv;
        dr = inv * (1.0f / 3000.0f);
    };

    float b1 = 0.0f;
    float P1, pv, dr;
    load_pre(ts - WARM, P1, pv, dr);

    for (int j = -WARM; j < CHUNK; ++j) {
        const int t = ts + j;
        // prefetch next step's scalars (independent of this step's compute)
        float nP1, npv, ndr;
        load_pre(t + 1, nP1, npv, ndr);

        // dp_a = P1*b1 + P2*v   (P0 == 1 -> a0 term vanishes)
        const float dp_a = fmaf(P1, b1, pv);

        // ---- input layer as MFMA: D_in = Wi*[dp_a, dr] + b_in, with exact
        //      f16 residual refinement at k=2,3 ----
        u32 w0 = packp(dp_a, dr);
        f16x2 hi2 = __builtin_bit_cast(f16x2, w0);
        u32 w1 = packp(dp_a - (float)hi2[0], dr - (float)hi2[1]);
        f16x8 BX = __builtin_bit_cast(f16x8, (u32x4){w0 & hm, w1 & hm, 0u, 0u});
        f32x16 acc = MFMA(AIN, BX, bINf);

        // relu(D) IS the next B (k-remap): B0 <- regs 0..7, B1 <- regs 8..15
        float v0[16];
#pragma unroll
        for (int r = 0; r < 16; ++r)
            v0[r] = fmaxf(acc[r], 0.0f);

        f16x8 B0 = __builtin_bit_cast(f16x8, (u32x4){
            packp(v0[0], v0[1]), packp(v0[2], v0[3]),
            packp(v0[4], v0[5]), packp(v0[6], v0[7])});
        f16x8 B1 = __builtin_bit_cast(f16x8, (u32x4){
            packp(v0[8], v0[9]), packp(v0[10], v0[11]),
            packp(v0[12], v0[13]), packp(v0[14], v0[15])});

        // ---- hidden layer A ----
        acc = MFMA(AA0, B0, bAf);
        acc = MFMA(AA1, B1, acc);

        float v1[16];
#pragma unroll
        for (int r = 0; r < 16; ++r)
            v1[r] = fmaxf(acc[r], 0.0f);

        B0 = __builtin_bit_cast(f16x8, (u32x4){
            packp(v1[0], v1[1]), packp(v1[2], v1[3]),
            packp(v1[4], v1[5]), packp(v1[6], v1[7])});
        B1 = __builtin_bit_cast(f16x8, (u32x4){
            packp(v1[8], v1[9]), packp(v1[10], v1[11]),
            packp(v1[12], v1[13]), packp(v1[14], v1[15])});

        // ---- hidden layer B ----
        acc = MFMA(AB0, B0, bBf);
        acc = MFMA(AB1, B1, acc);

        // ---- output layer 32->1: per-lane partial dot over C/D rows ----
        float p0 = 0.f, p1 = 0.f, p2 = 0.f, p3 = 0.f;
#pragma unroll
        for (int r = 0; r < 16; r += 4) {
            p0 = fmaf(wo_r[r],     fmaxf(acc[r],     0.0f), p0);
            p1 = fmaf(wo_r[r + 1], fmaxf(acc[r + 1], 0.0f), p1);
            p2 = fmaf(wo_r[r + 2], fmaxf(acc[r + 2], 0.0f), p2);
            p3 = fmaf(wo_r[r + 3], fmaxf(acc[r + 3], 0.0f), p3);
        }
        float pd = (p0 + p1) + (p2 + p3);

        // cross-half combine on the VALU: after the swap (dst-hi <-> src-lo,
        // identical inputs) pa[l] = pd[l&31], pb[l] = pd[l|32]. Every lane
        // forms pd_lo + pd_hi with the same add order -> bit-identical halves.
        float pa = pd, pb = pd;
        asm("v_permlane32_swap_b32 %0, %1" : "+v"(pa), "+v"(pb));
        const float dp_b = pa + pb + bo;

        const float sum = dp_a + dp_b;
        if (j >= 0) {                 // wave-uniform branch
            if (lane < 32 && t < T) out[t] = 0.5f * sum;
        }
        b1 = sum - b1;                // b1' = dp_b + (P1-1)*b1 + P2*v
        if (t < 0) b1 = 0.0f;         // warm-up clamp: exact b1=0 entering t=0

        P1 = nP1; pv = npv; dr = ndr;
    }
}

extern "C" void kernel_launch(void* const* d_in, const int* in_sizes, int n_in,
                              void* d_out, int out_size, void* d_ws, size_t ws_size,
                              hipStream_t stream) {
    const float* v_in  = (const float*)d_in[0];
    const float* vs_r  = (const float*)d_in[1];
    const float* fs    = (const float*)d_in[2];
    const float* W_in  = (const float*)d_in[3];
    const float* b_in  = (const float*)d_in[4];
    const float* W_h   = (const float*)d_in[5];
    const float* b_h   = (const float*)d_in[6];
    const float* W_out = (const float*)d_in[7];
    const float* b_out = (const float*)d_in[8];
    float* out = (float*)d_out;

    const int T = in_sizes[0];
    const int nChunks = (T + CHUNK - 1) / CHUNK;
    const int nWaves  = (nChunks + CPW - 1) / CPW;

    scan_kernel<<<nWaves, 64, 0, stream>>>(
        v_in, vs_r, fs, W_in, b_in, W_h, b_h, W_out, b_out, out, T);
}

// Round 5
// 88.519 us; speedup vs baseline: 1.0177x; 1.0128x over previous
//
#include <hip/hip_runtime.h>
#include <hip/hip_bf16.h>

#define C1_CONST 4.7e-9f
#define CHUNK 5       // output steps per chunk (3000 waves -> ~2.9 waves/SIMD)
#define WARM  10      // warm-up steps; |rho|~0.5 measured -> init err ~5e-4 < f16 floor
#define CPW   32      // chunks per wave (MFMA batch)
#define SPAN  192     // staged elements per wave: 3*64 >= WARM + CPW*CHUNK + 1 = 171

typedef _Float16 f16;
typedef unsigned int u32;
typedef int   i32x2  __attribute__((ext_vector_type(2)));
typedef f16   f16x2  __attribute__((ext_vector_type(2)));
typedef f16   f16x8  __attribute__((ext_vector_type(8)));
typedef u32   u32x4  __attribute__((ext_vector_type(4)));
typedef float f32x16 __attribute__((ext_vector_type(16)));

#define MFMA(A, B, C) __builtin_amdgcn_mfma_f32_32x32x16_f16((A), (B), (C), 0, 0, 0)

// Pack two f32 -> packed f16 pair (single v_cvt_pkrtz, RTZ).
__device__ __forceinline__ u32 packp(float x0, float x1) {
    return __builtin_bit_cast(u32, __builtin_amdgcn_cvt_pkrtz(x0, x1));
}

// Cross-half combine: every lane gets (pd[l&31], pd[l|32]).
// NEVER use asm("v_permlane32_swap_b32 %0,%1":"+v"(a),"+v"(b)) with a==b==pd:
// "+v" ties outputs to inputs and identical inputs may share ONE VGPR ->
// `v_permlane32_swap_b32 v5,v5` (pure half-swap). The SSA-modeled builtin
// returns both results; the compiler owns register constraints.
__device__ __forceinline__ void half_swap(float pd, float& lo, float& hi) {
#if __has_builtin(__builtin_amdgcn_permlane32_swap)
    i32x2 sw = __builtin_amdgcn_permlane32_swap(
        __float_as_int(pd), __float_as_int(pd), false, false);
    lo = __int_as_float(sw.x);   // pd[l&31]
    hi = __int_as_float(sw.y);   // pd[l|32]
#else
    float pa, pb;
    asm("v_mov_b32 %0, %2\n\t"
        "v_mov_b32 %1, %2\n\t"
        "v_permlane32_swap_b32 %0, %1"
        : "=&v"(pa), "=&v"(pb) : "v"(pd));
    lo = pa; hi = pb;
#endif
}

// r18: r15 structure (ROLLED loop, distance-1 prefetch, builtin permlane)
// + LDS input staging. r17's register-ring/full-unroll variant hit an
// unexplained post-timing divergence (launch 1 bit-exact, later launches
// consistently off by ~max|ref|) -> structural retreat to the passing shape.
// Latency theory unchanged: harness poison fills evict L2/L3 every replay,
// so r15's per-step 3-address gather missed to HBM (~900cy) against a
// ~330cy compute chain. Fix here: each wave stages its whole input span
// (192 elems, 9 coalesced dword loads) into LDS up front and precomputes
// the (P1, pv, dr) triples ONCE (bit-identical FP ops to r15's per-step
// load_pre). Step loop reads LDS (~120cy, hidden by distance-1 prefetch).
// In-loop LDS reads are conflict-free: element stride 5/lane, 5 coprime 32;
// lanes c and c+32 read the same address (free broadcast).
//
// Carried structure:
//  * Input layer 2->32 folded into a 5th MFMA, exact f16-residual refinement
//    at k=2,3 (input re-enters at ~f32 precision).
//  * amdgpu_waves_per_eu(2,3): grid is 2.9 waves/SIMD.
//
// LOGICAL-K REMAP (exact): k = (jj&3) + 4*h + 8*(jj>>2) + 16*s, so half h's
// B k-set equals the C/D rows it owns (row=(reg&3)+8*(reg>>2)+4*h) and
// D reg r = jj + 8*s: B0 = relu(D[0..7]), B1 = relu(D[8..15]).
//
// Uses the P0 == 1 identity (g0 = g1+g2 exactly), so the a0 carry vanishes:
//   dp_a = P1*b1 + P2*v,  b1' = dp_a + dp_b - b1,  out = 0.5*(dp_a+dp_b)
__global__ __attribute__((amdgpu_flat_work_group_size(64, 64), amdgpu_waves_per_eu(2, 3)))
void scan_kernel(
    const float* __restrict__ v_in, const float* __restrict__ vs_r,
    const float* __restrict__ fs,
    const float* __restrict__ W_in, const float* __restrict__ b_in,
    const float* __restrict__ W_h,  const float* __restrict__ b_h,
    const float* __restrict__ W_out, const float* __restrict__ b_out,
    float* __restrict__ out, int T) {
    const int lane = threadIdx.x & 63;
    const int c    = lane & 31;   // chunk slot / MFMA col / weight row m
    const int h    = lane >> 5;

    __shared__ float sP[SPAN], sV[SPAN], sD[SPAN];

    // ---- stage this wave's input span into LDS, precomputing the triples.
    // Element e holds step t = base + e. Same FP ops as r15's load_pre ->
    // bit-identical values, just computed once instead of per step.
    const int base = blockIdx.x * (CPW * CHUNK) - WARM;
#pragma unroll
    for (int q = 0; q < 3; ++q) {
        int e  = lane + 64 * q;
        int tc = min(max(base + e, 0), T - 1);
        float f  = fs[tc];
        float vr = vs_r[tc];
        float vv = v_in[tc];
        float g1 = (2.0f * C1_CONST) * f;
        float g2 = __builtin_amdgcn_rcpf(vr);
        float inv = __builtin_amdgcn_rcpf(g1 + g2);
        sP[e] = g1 * inv;
        sV[e] = g2 * inv * vv;
        sD[e] = inv * (1.0f / 3000.0f);
    }

    // ---- MFMA A fragments (f16) for the two hidden layers ----
    f16x8 AA0, AA1, AB0, AB1;
#pragma unroll
    for (int jj = 0; jj < 8; ++jj) {
        int k0 = (jj & 3) + 4 * h + 8 * (jj >> 2);   // s=0
        int k1 = k0 + 16;                            // s=1
        AA0[jj] = (f16)W_h[c * 32 + k0];
        AA1[jj] = (f16)W_h[c * 32 + k1];
        AB0[jj] = (f16)W_h[1024 + c * 32 + k0];
        AB1[jj] = (f16)W_h[1024 + c * 32 + k1];
    }

    // ---- input-layer MFMA A fragment (h==0 lanes only hold k=0..3,8..11):
    //      k=0,1 : weights on (dp_a, dr);  k=2,3 : SAME weights for the
    //      f16-residual refinement terms.
    f16x8 AIN;
#pragma unroll
    for (int jj = 0; jj < 8; ++jj) AIN[jj] = (f16)0.0f;
    if (h == 0) {
        f16 w0 = (f16)W_in[2 * c];
        f16 w1 = (f16)W_in[2 * c + 1];
        AIN[0] = w0;   // k=0: hi(dp_a)
        AIN[1] = w1;   // k=1: hi(dr)
        AIN[2] = w0;   // k=2: res(dp_a)
        AIN[3] = w1;   // k=3: res(dr)
    }

    // ---- biases in C/D layout; W_out by C/D row ----
    f32x16 bINf, bAf, bBf;
    float wo_r[16];
#pragma unroll
    for (int r = 0; r < 16; ++r) {
        int row = (r & 3) + 8 * (r >> 2) + 4 * h;
        bINf[r] = b_in[row];
        bAf[r]  = b_h[row];
        bBf[r]  = b_h[32 + row];
        wo_r[r] = W_out[row];
    }
    const float bo = b_out[0];
    const u32 hm   = h ? 0u : 0xFFFFFFFFu;   // kills B_x on h==1 lanes (belt+braces)

    const int cg = blockIdx.x * CPW + c;   // global chunk id
    const int ts = cg * CHUNK;             // first output step of this chunk

    __syncthreads();   // single wave: cheap; guarantees ds_write -> ds_read order

    // lane c consumes elements e = c*CHUNK + (j+WARM); max read e = 170 < 192.
    float b1 = 0.0f;
    int e = c * CHUNK;                     // element for j = -WARM
    float P1 = sP[e], pv = sV[e], dr = sD[e];

    for (int j = -WARM; j < CHUNK; ++j) {
        const int t = ts + j;
        // distance-1 prefetch of next step's triple from LDS (hidden under MFMAs)
        const int en = e + 1;
        float nP1 = sP[en], npv = sV[en], ndr = sD[en];

        // dp_a = P1*b1 + P2*v   (P0 == 1 -> a0 term vanishes)
        const float dp_a = fmaf(P1, b1, pv);

        // ---- input layer as MFMA: D_in = Wi*[dp_a, dr] + b_in, with exact
        //      f16 residual refinement at k=2,3 ----
        u32 w0 = packp(dp_a, dr);
        f16x2 hi2 = __builtin_bit_cast(f16x2, w0);
        u32 w1 = packp(dp_a - (float)hi2[0], dr - (float)hi2[1]);
        f16x8 BX = __builtin_bit_cast(f16x8, (u32x4){w0 & hm, w1 & hm, 0u, 0u});
        f32x16 acc = MFMA(AIN, BX, bINf);

        // relu(D) IS the next B (k-remap): B0 <- regs 0..7, B1 <- regs 8..15
        float v0[16];
#pragma unroll
        for (int r = 0; r < 16; ++r)
            v0[r] = fmaxf(acc[r], 0.0f);

        f16x8 B0 = __builtin_bit_cast(f16x8, (u32x4){
            packp(v0[0], v0[1]), packp(v0[2], v0[3]),
            packp(v0[4], v0[5]), packp(v0[6], v0[7])});
        f16x8 B1 = __builtin_bit_cast(f16x8, (u32x4){
            packp(v0[8], v0[9]), packp(v0[10], v0[11]),
            packp(v0[12], v0[13]), packp(v0[14], v0[15])});

        // ---- hidden layer A ----
        acc = MFMA(AA0, B0, bAf);
        acc = MFMA(AA1, B1, acc);

        float v1[16];
#pragma unroll
        for (int r = 0; r < 16; ++r)
            v1[r] = fmaxf(acc[r], 0.0f);

        B0 = __builtin_bit_cast(f16x8, (u32x4){
            packp(v1[0], v1[1]), packp(v1[2], v1[3]),
            packp(v1[4], v1[5]), packp(v1[6], v1[7])});
        B1 = __builtin_bit_cast(f16x8, (u32x4){
            packp(v1[8], v1[9]), packp(v1[10], v1[11]),
            packp(v1[12], v1[13]), packp(v1[14], v1[15])});

        // ---- hidden layer B ----
        acc = MFMA(AB0, B0, bBf);
        acc = MFMA(AB1, B1, acc);

        // ---- output layer 32->1: per-lane partial dot over C/D rows ----
        float p0 = 0.f, p1 = 0.f, p2 = 0.f, p3 = 0.f;
#pragma unroll
        for (int r = 0; r < 16; r += 4) {
            p0 = fmaf(wo_r[r],     fmaxf(acc[r],     0.0f), p0);
            p1 = fmaf(wo_r[r + 1], fmaxf(acc[r + 1], 0.0f), p1);
            p2 = fmaf(wo_r[r + 2], fmaxf(acc[r + 2], 0.0f), p2);
            p3 = fmaf(wo_r[r + 3], fmaxf(acc[r + 3], 0.0f), p3);
        }
        float pd = (p0 + p1) + (p2 + p3);

        // cross-half combine: every lane forms pd_lo + pd_hi in the same
        // order -> bit-identical halves (pair (c, c+32) carries one chunk).
        float plo, phi;
        half_swap(pd, plo, phi);
        const float dp_b = plo + phi + bo;

        const float sum = dp_a + dp_b;
        if (j >= 0) {                 // wave-uniform branch
            if (lane < 32 && t < T) out[t] = 0.5f * sum;
        }
        b1 = sum - b1;                // b1' = dp_b + (P1-1)*b1 + P2*v
        if (t < 0) b1 = 0.0f;         // warm-up clamp: exact b1=0 entering t=0

        P1 = nP1; pv = npv; dr = ndr; e = en;
    }
}

extern "C" void kernel_launch(void* const* d_in, const int* in_sizes, int n_in,
                              void* d_out, int out_size, void* d_ws, size_t ws_size,
                              hipStream_t stream) {
    const float* v_in  = (const float*)d_in[0];
    const float* vs_r  = (const float*)d_in[1];
    const float* fs    = (const float*)d_in[2];
    const float* W_in  = (const float*)d_in[3];
    const float* b_in  = (const float*)d_in[4];
    const float* W_h   = (const float*)d_in[5];
    const float* b_h   = (const float*)d_in[6];
    const float* W_out = (const float*)d_in[7];
    const float* b_out = (const float*)d_in[8];
    float* out = (float*)d_out;

    const int T = in_sizes[0];
    const int nChunks = (T + CHUNK - 1) / CHUNK;
    const int nWaves  = (nChunks + CPW - 1) / CPW;

    scan_kernel<<<nWaves, 64, 0, stream>>>(
        v_in, vs_r, fs, W_in, b_in, W_h, b_h, W_out, b_out, out, T);
}

// Round 6
// 83.848 us; speedup vs baseline: 1.0744x; 1.0557x over previous
//
#include <hip/hip_runtime.h>
#include <hip/hip_bf16.h>

#define C1_CONST 4.7e-9f
#define CHUNK 8       // output steps per chunk: 18 steps/8 outputs (was 15/5)
                      // -> 25% fewer total step-rows; 1875 waves = 1.83/SIMD,
                      // issue (~2x18x175cy) ~ latency (18x330cy) balanced.
#define WARM  10      // warm-up steps; |rho|~0.5 -> init err ~5e-4, CHUNK-indep
#define CPW   32      // chunks per wave (MFMA batch)
#define SPAN  320     // staged elements: 5*64 >= WARM + CPW*CHUNK + 1 = 267

typedef _Float16 f16;
typedef unsigned int u32;
typedef int   i32x2  __attribute__((ext_vector_type(2)));
typedef f16   f16x2  __attribute__((ext_vector_type(2)));
typedef f16   f16x8  __attribute__((ext_vector_type(8)));
typedef u32   u32x4  __attribute__((ext_vector_type(4)));
typedef float f32x16 __attribute__((ext_vector_type(16)));

#define MFMA(A, B, C) __builtin_amdgcn_mfma_f32_32x32x16_f16((A), (B), (C), 0, 0, 0)

// Pack two f32 -> packed f16 pair (single v_cvt_pkrtz, RTZ).
__device__ __forceinline__ u32 packp(float x0, float x1) {
    return __builtin_bit_cast(u32, __builtin_amdgcn_cvt_pkrtz(x0, x1));
}

// Packed f16 relu (v_pk_max_f16). BIT-IDENTICAL to relu-in-f32-then-pack:
// cvt_pkrtz is monotonic, cvt(0)=0, no NaNs; -0 vs +0 is invisible to MFMA.
// Replaces {16 v_max_f32 + 8 cvt} with {8 cvt + 8 pk_max} per transition.
__device__ __forceinline__ u32 pkmax0(u32 x) {
    f16x2 v = __builtin_bit_cast(f16x2, x);
    f16x2 z = {(f16)0.0f, (f16)0.0f};
    return __builtin_bit_cast(u32, __builtin_elementwise_max(v, z));
}

// Cross-half combine: every lane gets (pd[l&31], pd[l|32]).
// NEVER use asm("v_permlane32_swap_b32 %0,%1":"+v"(a),"+v"(b)) with a==b==pd:
// "+v" ties outputs to inputs and identical inputs may share ONE VGPR ->
// `v_permlane32_swap_b32 v5,v5` (pure half-swap). The SSA-modeled builtin
// returns both results; the compiler owns register constraints.
__device__ __forceinline__ void half_swap(float pd, float& lo, float& hi) {
#if __has_builtin(__builtin_amdgcn_permlane32_swap)
    i32x2 sw = __builtin_amdgcn_permlane32_swap(
        __float_as_int(pd), __float_as_int(pd), false, false);
    lo = __int_as_float(sw.x);   // pd[l&31]
    hi = __int_as_float(sw.y);   // pd[l|32]
#else
    float pa, pb;
    asm("v_mov_b32 %0, %2\n\t"
        "v_mov_b32 %1, %2\n\t"
        "v_permlane32_swap_b32 %0, %1"
        : "=&v"(pa), "=&v"(pb) : "v"(pd));
    lo = pa; hi = pb;
#endif
}

// r19 = r18 + {CHUNK 5->8, packed-f16 relu}. Model: kernel part (~7.1us of
// the 88.5; rest is 2x256MB harness poison fills at ~40.7us) is VALU-issue
// bound: ~100 VALU/step x 2cy x 2.93 waves/SIMD = ~600cy/step vs ~330cy dep
// chain. CHUNK=8 cuts total step-rows 25% (warm-up amortized over 8 outputs)
// and lands 1.83 waves/SIMD where issue ~ latency; pk_max relu trims ~16
// VALU/step bit-identically. No numeric-path changes -> absmax must stay at
// the bf16 comparison floor 1.953e-3.
//
// Carried structure:
//  * LDS input staging: wave stages its whole span (9->15 coalesced loads),
//    triples computed once (same FP ops as per-step load_pre). In-loop LDS
//    reads conflict-free (stride 8 elems/lane; lanes c and c+32 same addr).
//  * Input layer 2->32 folded into a 5th MFMA, exact f16-residual refinement
//    at k=2,3 (input re-enters at ~f32 precision).
//  * amdgpu_waves_per_eu(2,3).
//
// LOGICAL-K REMAP (exact): k = (jj&3) + 4*h + 8*(jj>>2) + 16*s, so half h's
// B k-set equals the C/D rows it owns (row=(reg&3)+8*(reg>>2)+4*h) and
// D reg r = jj + 8*s: B0 = relu(D[0..7]), B1 = relu(D[8..15]).
//
// Uses the P0 == 1 identity (g0 = g1+g2 exactly), so the a0 carry vanishes:
//   dp_a = P1*b1 + P2*v,  b1' = dp_a + dp_b - b1,  out = 0.5*(dp_a+dp_b)
__global__ __attribute__((amdgpu_flat_work_group_size(64, 64), amdgpu_waves_per_eu(2, 3)))
void scan_kernel(
    const float* __restrict__ v_in, const float* __restrict__ vs_r,
    const float* __restrict__ fs,
    const float* __restrict__ W_in, const float* __restrict__ b_in,
    const float* __restrict__ W_h,  const float* __restrict__ b_h,
    const float* __restrict__ W_out, const float* __restrict__ b_out,
    float* __restrict__ out, int T) {
    const int lane = threadIdx.x & 63;
    const int c    = lane & 31;   // chunk slot / MFMA col / weight row m
    const int h    = lane >> 5;

    __shared__ float sP[SPAN], sV[SPAN], sD[SPAN];

    // ---- stage this wave's input span into LDS, precomputing the triples.
    // Element e holds step t = base + e. Same FP ops as the per-step
    // load_pre of r15 -> bit-identical values, computed once.
    const int base = blockIdx.x * (CPW * CHUNK) - WARM;
#pragma unroll
    for (int q = 0; q < SPAN / 64; ++q) {
        int e  = lane + 64 * q;
        int tc = min(max(base + e, 0), T - 1);
        float f  = fs[tc];
        float vr = vs_r[tc];
        float vv = v_in[tc];
        float g1 = (2.0f * C1_CONST) * f;
        float g2 = __builtin_amdgcn_rcpf(vr);
        float inv = __builtin_amdgcn_rcpf(g1 + g2);
        sP[e] = g1 * inv;
        sV[e] = g2 * inv * vv;
        sD[e] = inv * (1.0f / 3000.0f);
    }

    // ---- MFMA A fragments (f16) for the two hidden layers ----
    f16x8 AA0, AA1, AB0, AB1;
#pragma unroll
    for (int jj = 0; jj < 8; ++jj) {
        int k0 = (jj & 3) + 4 * h + 8 * (jj >> 2);   // s=0
        int k1 = k0 + 16;                            // s=1
        AA0[jj] = (f16)W_h[c * 32 + k0];
        AA1[jj] = (f16)W_h[c * 32 + k1];
        AB0[jj] = (f16)W_h[1024 + c * 32 + k0];
        AB1[jj] = (f16)W_h[1024 + c * 32 + k1];
    }

    // ---- input-layer MFMA A fragment (h==0 lanes only hold k=0..3,8..11):
    //      k=0,1 : weights on (dp_a, dr);  k=2,3 : SAME weights for the
    //      f16-residual refinement terms.
    f16x8 AIN;
#pragma unroll
    for (int jj = 0; jj < 8; ++jj) AIN[jj] = (f16)0.0f;
    if (h == 0) {
        f16 w0 = (f16)W_in[2 * c];
        f16 w1 = (f16)W_in[2 * c + 1];
        AIN[0] = w0;   // k=0: hi(dp_a)
        AIN[1] = w1;   // k=1: hi(dr)
        AIN[2] = w0;   // k=2: res(dp_a)
        AIN[3] = w1;   // k=3: res(dr)
    }

    // ---- biases in C/D layout; W_out by C/D row ----
    f32x16 bINf, bAf, bBf;
    float wo_r[16];
#pragma unroll
    for (int r = 0; r < 16; ++r) {
        int row = (r & 3) + 8 * (r >> 2) + 4 * h;
        bINf[r] = b_in[row];
        bAf[r]  = b_h[row];
        bBf[r]  = b_h[32 + row];
        wo_r[r] = W_out[row];
    }
    const float bo = b_out[0];
    const u32 hm   = h ? 0u : 0xFFFFFFFFu;   // kills B_x on h==1 lanes (belt+braces)

    const int cg = blockIdx.x * CPW + c;   // global chunk id
    const int ts = cg * CHUNK;             // first output step of this chunk

    __syncthreads();   // single wave: cheap; guarantees ds_write -> ds_read order

    // lane c consumes elements e = c*CHUNK + (j+WARM); max read e = 265 < 320.
    float b1 = 0.0f;
    int e = c * CHUNK;                     // element for j = -WARM
    float P1 = sP[e], pv = sV[e], dr = sD[e];

    for (int j = -WARM; j < CHUNK; ++j) {
        const int t = ts + j;
        // distance-1 prefetch of next step's triple from LDS (hidden under MFMAs)
        const int en = e + 1;
        float nP1 = sP[en], npv = sV[en], ndr = sD[en];

        // dp_a = P1*b1 + P2*v   (P0 == 1 -> a0 term vanishes)
        const float dp_a = fmaf(P1, b1, pv);

        // ---- input layer as MFMA: D_in = Wi*[dp_a, dr] + b_in, with exact
        //      f16 residual refinement at k=2,3 ----
        u32 w0 = packp(dp_a, dr);
        f16x2 hi2 = __builtin_bit_cast(f16x2, w0);
        u32 w1 = packp(dp_a - (float)hi2[0], dr - (float)hi2[1]);
        f16x8 BX = __builtin_bit_cast(f16x8, (u32x4){w0 & hm, w1 & hm, 0u, 0u});
        f32x16 acc = MFMA(AIN, BX, bINf);

        // relu(D) IS the next B (k-remap): pack pairs then packed relu.
        u32 pk[8];
#pragma unroll
        for (int r = 0; r < 8; ++r)
            pk[r] = pkmax0(packp(acc[2 * r], acc[2 * r + 1]));
        f16x8 B0 = __builtin_bit_cast(f16x8, (u32x4){pk[0], pk[1], pk[2], pk[3]});
        f16x8 B1 = __builtin_bit_cast(f16x8, (u32x4){pk[4], pk[5], pk[6], pk[7]});

        // ---- hidden layer A ----
        acc = MFMA(AA0, B0, bAf);
        acc = MFMA(AA1, B1, acc);

#pragma unroll
        for (int r = 0; r < 8; ++r)
            pk[r] = pkmax0(packp(acc[2 * r], acc[2 * r + 1]));
        B0 = __builtin_bit_cast(f16x8, (u32x4){pk[0], pk[1], pk[2], pk[3]});
        B1 = __builtin_bit_cast(f16x8, (u32x4){pk[4], pk[5], pk[6], pk[7]});

        // ---- hidden layer B ----
        acc = MFMA(AB0, B0, bBf);
        acc = MFMA(AB1, B1, acc);

        // ---- output layer 32->1: per-lane partial dot over C/D rows (f32) ----
        float p0 = 0.f, p1 = 0.f, p2 = 0.f, p3 = 0.f;
#pragma unroll
        for (int r = 0; r < 16; r += 4) {
            p0 = fmaf(wo_r[r],     fmaxf(acc[r],     0.0f), p0);
            p1 = fmaf(wo_r[r + 1], fmaxf(acc[r + 1], 0.0f), p1);
            p2 = fmaf(wo_r[r + 2], fmaxf(acc[r + 2], 0.0f), p2);
            p3 = fmaf(wo_r[r + 3], fmaxf(acc[r + 3], 0.0f), p3);
        }
        float pd = (p0 + p1) + (p2 + p3);

        // cross-half combine: every lane forms pd_lo + pd_hi in the same
        // order -> bit-identical halves (pair (c, c+32) carries one chunk).
        float plo, phi;
        half_swap(pd, plo, phi);
        const float dp_b = plo + phi + bo;

        const float sum = dp_a + dp_b;
        if (j >= 0) {                 // wave-uniform branch
            if (lane < 32 && t < T) out[t] = 0.5f * sum;
        }
        b1 = sum - b1;                // b1' = dp_b + (P1-1)*b1 + P2*v
        if (t < 0) b1 = 0.0f;         // warm-up clamp: exact b1=0 entering t=0

        P1 = nP1; pv = npv; dr = ndr; e = en;
    }
}

extern "C" void kernel_launch(void* const* d_in, const int* in_sizes, int n_in,
                              void* d_out, int out_size, void* d_ws, size_t ws_size,
                              hipStream_t stream) {
    const float* v_in  = (const float*)d_in[0];
    const float* vs_r  = (const float*)d_in[1];
    const float* fs    = (const float*)d_in[2];
    const float* W_in  = (const float*)d_in[3];
    const float* b_in  = (const float*)d_in[4];
    const float* W_h   = (const float*)d_in[5];
    const float* b_h   = (const float*)d_in[6];
    const float* W_out = (const float*)d_in[7];
    const float* b_out = (const float*)d_in[8];
    float* out = (float*)d_out;

    const int T = in_sizes[0];
    const int nChunks = (T + CHUNK - 1) / CHUNK;
    const int nWaves  = (nChunks + CPW - 1) / CPW;

    scan_kernel<<<nWaves, 64, 0, stream>>>(
        v_in, vs_r, fs, W_in, b_in, W_h, b_h, W_out, b_out, out, T);
}

// Round 7
// 82.725 us; speedup vs baseline: 1.0889x; 1.0136x over previous
//
#include <hip/hip_runtime.h>
#include <hip/hip_bf16.h>

#define C1_CONST 4.7e-9f
#define CHUNK 8       // output steps per chunk: 18 steps/8 outputs
                      // -> 1875 waves = 1.83/SIMD; issue ~ latency balanced.
#define WARM  10      // warm-up steps; |rho|~0.5 -> init err ~5e-4, CHUNK-indep
#define CPW   32      // chunks per wave (MFMA batch)
#define SPAN  320     // staged elements: 5*64 >= WARM + CPW*CHUNK + 1 = 267

typedef _Float16 f16;
typedef unsigned int u32;
typedef int   i32x2  __attribute__((ext_vector_type(2)));
typedef f16   f16x2  __attribute__((ext_vector_type(2)));
typedef f16   f16x8  __attribute__((ext_vector_type(8)));
typedef u32   u32x4  __attribute__((ext_vector_type(4)));
typedef float f32x16 __attribute__((ext_vector_type(16)));

#define MFMA(A, B, C) __builtin_amdgcn_mfma_f32_32x32x16_f16((A), (B), (C), 0, 0, 0)

// Pack two f32 -> packed f16 pair (single v_cvt_pkrtz, RTZ).
__device__ __forceinline__ u32 packp(float x0, float x1) {
    return __builtin_bit_cast(u32, __builtin_amdgcn_cvt_pkrtz(x0, x1));
}

// Packed f16 relu (v_pk_max_f16). BIT-IDENTICAL to relu-in-f32-then-pack:
// cvt_pkrtz is monotonic, cvt(0)=0, no NaNs; -0 vs +0 is invisible to MFMA.
__device__ __forceinline__ u32 pkmax0(u32 x) {
    f16x2 v = __builtin_bit_cast(f16x2, x);
    f16x2 z = {(f16)0.0f, (f16)0.0f};
    return __builtin_bit_cast(u32, __builtin_elementwise_max(v, z));
}

// Cross-half broadcast/combine: every lane gets (x[l&31], x[l|32]).
// NEVER use asm("v_permlane32_swap_b32 %0,%1":"+v"(a),"+v"(b)) with a==b:
// "+v" ties outputs to inputs and identical inputs may share ONE VGPR ->
// `v_permlane32_swap_b32 v5,v5` (pure half-swap). The SSA-modeled builtin
// returns both results; the compiler owns register constraints.
__device__ __forceinline__ void half_swap(float pd, float& lo, float& hi) {
#if __has_builtin(__builtin_amdgcn_permlane32_swap)
    i32x2 sw = __builtin_amdgcn_permlane32_swap(
        __float_as_int(pd), __float_as_int(pd), false, false);
    lo = __int_as_float(sw.x);   // x[l&31]
    hi = __int_as_float(sw.y);   // x[l|32]
#else
    float pa, pb;
    asm("v_mov_b32 %0, %2\n\t"
        "v_mov_b32 %1, %2\n\t"
        "v_permlane32_swap_b32 %0, %1"
        : "=&v"(pa), "=&v"(pb) : "v"(pd));
    lo = pa; hi = pb;
#endif
}

// r20 = r19 + output layer 32->1 as a 6th MFMA. The f32 output dot was the
// fattest remaining VALU block (16 max + 16 fma + 6 adds ~ 76cy/step/wave of
// the ~180cy issue budget). relu(layer-B D) is ALREADY the next-B operand
// under the k-remap (same pk pack as hidden transitions); A_out row 0 = W_out
// in the same permuted k-order (only lanes c==0 populated, rows 1-31 zero);
// b_out rides in the C operand at reg 0 (h==0). D[0][c] IS dp_b for chunk c,
// broadcast to lane c+32 by the same permlane32_swap (lo = x[l&31]) -- both
// halves now consume literally one value, so half-identity is trivial.
// Precision: output dot operands f32->f16 (same quantization family as the
// hidden layers); expected added noise ~5e-4 against 7x threshold headroom.
//
// Carried structure:
//  * LDS input staging; triples computed once (bit-identical to per-step).
//    In-loop LDS reads conflict-free (stride 8 elems/lane; c and c+32 same
//    address -> broadcast).
//  * Input layer 2->32 folded into a 5th MFMA, exact f16-residual refinement
//    at k=2,3 (input re-enters at ~f32 precision).
//  * CHUNK=8/WARM=10 (18 steps per 8 outputs, 1875 waves).
//  * amdgpu_waves_per_eu(2,3).
//
// LOGICAL-K REMAP (exact): k = (jj&3) + 4*h + 8*(jj>>2) + 16*s, so half h's
// B k-set equals the C/D rows it owns (row=(reg&3)+8*(reg>>2)+4*h) and
// D reg r = jj + 8*s: B0 = relu(D[0..7]), B1 = relu(D[8..15]).
//
// Uses the P0 == 1 identity (g0 = g1+g2 exactly), so the a0 carry vanishes:
//   dp_a = P1*b1 + P2*v,  b1' = dp_a + dp_b - b1,  out = 0.5*(dp_a+dp_b)
__global__ __attribute__((amdgpu_flat_work_group_size(64, 64), amdgpu_waves_per_eu(2, 3)))
void scan_kernel(
    const float* __restrict__ v_in, const float* __restrict__ vs_r,
    const float* __restrict__ fs,
    const float* __restrict__ W_in, const float* __restrict__ b_in,
    const float* __restrict__ W_h,  const float* __restrict__ b_h,
    const float* __restrict__ W_out, const float* __restrict__ b_out,
    float* __restrict__ out, int T) {
    const int lane = threadIdx.x & 63;
    const int c    = lane & 31;   // chunk slot / MFMA col / weight row m
    const int h    = lane >> 5;

    __shared__ float sP[SPAN], sV[SPAN], sD[SPAN];

    // ---- stage this wave's input span into LDS, precomputing the triples.
    // Element e holds step t = base + e. Same FP ops as the per-step
    // load_pre -> bit-identical values, computed once.
    const int base = blockIdx.x * (CPW * CHUNK) - WARM;
#pragma unroll
    for (int q = 0; q < SPAN / 64; ++q) {
        int e  = lane + 64 * q;
        int tc = min(max(base + e, 0), T - 1);
        float f  = fs[tc];
        float vr = vs_r[tc];
        float vv = v_in[tc];
        float g1 = (2.0f * C1_CONST) * f;
        float g2 = __builtin_amdgcn_rcpf(vr);
        float inv = __builtin_amdgcn_rcpf(g1 + g2);
        sP[e] = g1 * inv;
        sV[e] = g2 * inv * vv;
        sD[e] = inv * (1.0f / 3000.0f);
    }

    // ---- MFMA A fragments (f16) for the two hidden layers ----
    f16x8 AA0, AA1, AB0, AB1;
#pragma unroll
    for (int jj = 0; jj < 8; ++jj) {
        int k0 = (jj & 3) + 4 * h + 8 * (jj >> 2);   // s=0
        int k1 = k0 + 16;                            // s=1
        AA0[jj] = (f16)W_h[c * 32 + k0];
        AA1[jj] = (f16)W_h[c * 32 + k1];
        AB0[jj] = (f16)W_h[1024 + c * 32 + k0];
        AB1[jj] = (f16)W_h[1024 + c * 32 + k1];
    }

    // ---- input-layer MFMA A fragment (h==0 lanes only hold k=0..3,8..11):
    //      k=0,1 : weights on (dp_a, dr);  k=2,3 : SAME weights for the
    //      f16-residual refinement terms.
    f16x8 AIN;
#pragma unroll
    for (int jj = 0; jj < 8; ++jj) AIN[jj] = (f16)0.0f;
    if (h == 0) {
        f16 w0 = (f16)W_in[2 * c];
        f16 w1 = (f16)W_in[2 * c + 1];
        AIN[0] = w0;   // k=0: hi(dp_a)
        AIN[1] = w1;   // k=1: hi(dr)
        AIN[2] = w0;   // k=2: res(dp_a)
        AIN[3] = w1;   // k=3: res(dr)
    }

    // ---- output-layer MFMA A fragment: A-row 0 = W_out (lanes c==0 only),
    //      k-slots in the SAME permuted order as the B-side pack.
    f16x8 AO0, AO1;
#pragma unroll
    for (int jj = 0; jj < 8; ++jj) { AO0[jj] = (f16)0.0f; AO1[jj] = (f16)0.0f; }
    if (c == 0) {
#pragma unroll
        for (int jj = 0; jj < 8; ++jj) {
            int k = (jj & 3) + 4 * h + 8 * (jj >> 2);
            AO0[jj] = (f16)W_out[k];
            AO1[jj] = (f16)W_out[k + 16];
        }
    }

    // ---- biases in C/D layout ----
    f32x16 bINf, bAf, bBf, cOUT;
#pragma unroll
    for (int r = 0; r < 16; ++r) {
        int row = (r & 3) + 8 * (r >> 2) + 4 * h;
        bINf[r] = b_in[row];
        bAf[r]  = b_h[row];
        bBf[r]  = b_h[32 + row];
        cOUT[r] = 0.0f;
    }
    if (h == 0) cOUT[0] = b_out[0];   // C/D reg 0 is row 4h -> row 0 on h==0
    const u32 hm = h ? 0u : 0xFFFFFFFFu;   // kills B_x on h==1 lanes (belt+braces)

    const int cg = blockIdx.x * CPW + c;   // global chunk id
    const int ts = cg * CHUNK;             // first output step of this chunk

    __syncthreads();   // single wave: cheap; guarantees ds_write -> ds_read order

    // lane c consumes elements e = c*CHUNK + (j+WARM); max read e = 265 < 320.
    float b1 = 0.0f;
    int e = c * CHUNK;                     // element for j = -WARM
    float P1 = sP[e], pv = sV[e], dr = sD[e];

    for (int j = -WARM; j < CHUNK; ++j) {
        const int t = ts + j;
        // distance-1 prefetch of next step's triple from LDS (hidden under MFMAs)
        const int en = e + 1;
        float nP1 = sP[en], npv = sV[en], ndr = sD[en];

        // dp_a = P1*b1 + P2*v   (P0 == 1 -> a0 term vanishes)
        const float dp_a = fmaf(P1, b1, pv);

        // ---- input layer as MFMA: D_in = Wi*[dp_a, dr] + b_in, with exact
        //      f16 residual refinement at k=2,3 ----
        u32 w0 = packp(dp_a, dr);
        f16x2 hi2 = __builtin_bit_cast(f16x2, w0);
        u32 w1 = packp(dp_a - (float)hi2[0], dr - (float)hi2[1]);
        f16x8 BX = __builtin_bit_cast(f16x8, (u32x4){w0 & hm, w1 & hm, 0u, 0u});
        f32x16 acc = MFMA(AIN, BX, bINf);

        // relu(D) IS the next B (k-remap): pack pairs then packed relu.
        u32 pk[8];
#pragma unroll
        for (int r = 0; r < 8; ++r)
            pk[r] = pkmax0(packp(acc[2 * r], acc[2 * r + 1]));
        f16x8 B0 = __builtin_bit_cast(f16x8, (u32x4){pk[0], pk[1], pk[2], pk[3]});
        f16x8 B1 = __builtin_bit_cast(f16x8, (u32x4){pk[4], pk[5], pk[6], pk[7]});

        // ---- hidden layer A ----
        acc = MFMA(AA0, B0, bAf);
        acc = MFMA(AA1, B1, acc);

#pragma unroll
        for (int r = 0; r < 8; ++r)
            pk[r] = pkmax0(packp(acc[2 * r], acc[2 * r + 1]));
        B0 = __builtin_bit_cast(f16x8, (u32x4){pk[0], pk[1], pk[2], pk[3]});
        B1 = __builtin_bit_cast(f16x8, (u32x4){pk[4], pk[5], pk[6], pk[7]});

        // ---- hidden layer B ----
        acc = MFMA(AB0, B0, bBf);
        acc = MFMA(AB1, B1, acc);

        // ---- output layer 32->1 as MFMA: D[0][c] = b_out + wo . relu(hB) ----
#pragma unroll
        for (int r = 0; r < 8; ++r)
            pk[r] = pkmax0(packp(acc[2 * r], acc[2 * r + 1]));
        B0 = __builtin_bit_cast(f16x8, (u32x4){pk[0], pk[1], pk[2], pk[3]});
        B1 = __builtin_bit_cast(f16x8, (u32x4){pk[4], pk[5], pk[6], pk[7]});
        f32x16 acc2 = MFMA(AO0, B0, cOUT);
        acc2 = MFMA(AO1, B1, acc2);

        // dp_b lives on lane c (h==0), reg 0; broadcast to lane c+32.
        float dlo, dhi;
        half_swap(acc2[0], dlo, dhi);
        const float dp_b = dlo;           // = D[0][c] on both halves

        const float sum = dp_a + dp_b;
        if (j >= 0) {                 // wave-uniform branch
            if (lane < 32 && t < T) out[t] = 0.5f * sum;
        }
        b1 = sum - b1;                // b1' = dp_b + (P1-1)*b1 + P2*v
        if (t < 0) b1 = 0.0f;         // warm-up clamp: exact b1=0 entering t=0

        P1 = nP1; pv = npv; dr = ndr; e = en;
    }
}

extern "C" void kernel_launch(void* const* d_in, const int* in_sizes, int n_in,
                              void* d_out, int out_size, void* d_ws, size_t ws_size,
                              hipStream_t stream) {
    const float* v_in  = (const float*)d_in[0];
    const float* vs_r  = (const float*)d_in[1];
    const float* fs    = (const float*)d_in[2];
    const float* W_in  = (const float*)d_in[3];
    const float* b_in  = (const float*)d_in[4];
    const float* W_h   = (const float*)d_in[5];
    const float* b_h   = (const float*)d_in[6];
    const float* W_out = (const float*)d_in[7];
    const float* b_out = (const float*)d_in[8];
    float* out = (float*)d_out;

    const int T = in_sizes[0];
    const int nChunks = (T + CHUNK - 1) / CHUNK;
    const int nWaves  = (nChunks + CPW - 1) / CPW;

    scan_kernel<<<nWaves, 64, 0, stream>>>(
        v_in, vs_r, fs, W_in, b_in, W_h, b_h, W_out, b_out, out, T);
}